// Round 6
// baseline (119.686 us; speedup 1.0000x reference)
//
#include <hip/hip_runtime.h>

typedef unsigned short u16;
typedef short bf16x8 __attribute__((ext_vector_type(8)));
typedef float f32x4 __attribute__((ext_vector_type(4)));

#define BATCH 2
#define SEQ   2048
#define CH    1024
#define NHEAD 16
#define HDIM  64
#define ROWS  (BATCH*SEQ)   // 4096

// swizzled LDS index for [*][64] bf16 tiles: breaks 128B-row bank conflicts
#define SWZ(r_, c_) (((r_)*64) + ((c_) ^ (((r_)&7)*8)))

__device__ __forceinline__ u16 f2b(float f) {
  unsigned u = __builtin_bit_cast(unsigned, f);
  u += 0x7FFFu + ((u >> 16) & 1u);
  return (u16)(u >> 16);
}
__device__ __forceinline__ float b2f(u16 h) {
  unsigned u = ((unsigned)h) << 16;
  return __builtin_bit_cast(float, u);
}
__device__ __forceinline__ float exp2_fast(float x) {
  float r; asm("v_exp_f32 %0, %1" : "=v"(r) : "v"(x)); return r;
}
__device__ __forceinline__ unsigned cvt_pk_bf16(float a, float b) {
  unsigned r; asm("v_cvt_pk_bf16_f32 %0, %1, %2" : "=v"(r) : "v"(a), "v"(b)); return r;
}

__device__ __forceinline__ void gload_lds16(const void* g, void* l) {
  __builtin_amdgcn_global_load_lds(
      (const __attribute__((address_space(1))) unsigned int*)g,
      (__attribute__((address_space(3))) unsigned int*)l, 16, 0, 0);
}

// ---------- x (f32) -> bf16 [4096][1024] ----------
__global__ void csa_convert_x(const float* __restrict__ in, u16* __restrict__ out,
                              int n8) {
  int i = blockIdx.x * 256 + threadIdx.x;
  if (i >= n8) return;
  const float4* f4 = (const float4*)in;
  float4 v0 = f4[2*i], v1 = f4[2*i+1];
  ushort4 o0, o1;
  o0.x = f2b(v0.x); o0.y = f2b(v0.y); o0.z = f2b(v0.z); o0.w = f2b(v0.w);
  o1.x = f2b(v1.x); o1.y = f2b(v1.y); o1.z = f2b(v1.z); o1.w = f2b(v1.w);
  ((ushort4*)out)[2*i]   = o0;
  ((ushort4*)out)[2*i+1] = o1;
}

// ---------- both weights [1024][C] f32 -> Wt [C][1024] bf16, one launch ----------
__global__ void csa_transpose2(const float* __restrict__ wa, const float* __restrict__ wp,
                               u16* __restrict__ wat, u16* __restrict__ wpt) {
  __shared__ float tile[32][33];
  int bx = blockIdx.x;
  const float* in; u16* out; int C;
  if (bx < 96) { in = wa; out = wat; C = 3*CH; }
  else         { in = wp; out = wpt; C = CH; bx -= 96; }
  const int R = CH;
  const int bxc = bx * 32, by = blockIdx.y * 32;
  const int tx = threadIdx.x, ty = threadIdx.y;
  #pragma unroll
  for (int j = 0; j < 4; ++j) {
    int r = by + ty + j*8, c = bxc + tx;
    tile[ty + j*8][tx] = in[(size_t)r*C + c];
  }
  __syncthreads();
  #pragma unroll
  for (int j = 0; j < 4; ++j) {
    int oc = bxc + ty + j*8;   // column of in = row of out
    int orr = by + tx;         // row of in   = col of out
    out[(size_t)oc*R + orr] = f2b(tile[tx][ty + j*8]);
  }
}

// ---------- QKV GEMM: [4096][3072] = xb[4096][1024] * wat[3072][1024]^T + b ----
// BM=256, BN=192, BK=64; 512 thr = 8 waves (2M x 4N), per-wave 128x48.
// Grid 16x16 = 256 blocks = exactly 1/CU. 2-phase single-barrier dbuf.
// 2D-chunk XCD swizzle: each XCD gets a 4bm x 8bn region (~5MB footprint).
__global__ __launch_bounds__(512) void csa_gemm_qkv(
    const u16* __restrict__ A, const u16* __restrict__ Bt,
    const float* __restrict__ bias,
    u16* __restrict__ qbo, u16* __restrict__ kb, u16* __restrict__ vtb)
{
  __shared__ __align__(16) u16 As[2][256*64];   // 64 KB
  __shared__ __align__(16) u16 Bs[2][192*64];   // 48 KB
  const int t = threadIdx.x, lane = t & 63, w = t >> 6;
  const int wm = w >> 2, wn = w & 3, g = lane >> 4, qi = lane & 15;

  // bijective 2D-chunk swizzle over the 16x16 grid (8 chunks of 4bm x 8bn)
  const int wgid = blockIdx.y * 16 + blockIdx.x;
  const int c8 = wgid & 7, inner = wgid >> 3;
  const int bm = (c8 >> 1) * 4 + (inner >> 3);   // 0..15
  const int bn = (c8 & 1) * 8 + (inner & 7);     // 0..15

  f32x4 acc[8][3] = {};

  const u16* Ab = A  + (size_t)(bm*256)*CH;
  const u16* Bb = Bt + (size_t)(bn*192)*CH;
  const int srow = t >> 3;          // 0..63
  const int scol = (t & 7) * 8;

  // prologue: stage k0=0 into buf 0
  #pragma unroll
  for (int p = 0; p < 4; ++p)
    gload_lds16(Ab + (size_t)(p*64 + srow)*CH + scol, &As[0][p*4096 + w*512]);
  #pragma unroll
  for (int p = 0; p < 3; ++p)
    gload_lds16(Bb + (size_t)(p*64 + srow)*CH + scol, &Bs[0][p*4096 + w*512]);
  __syncthreads();

  int cur = 0;
  for (int k0 = 0; k0 < CH; k0 += 64) {
    if (k0 + 64 < CH) {   // prefetch next K-tile into buf^1
      #pragma unroll
      for (int p = 0; p < 4; ++p)
        gload_lds16(Ab + (size_t)(p*64 + srow)*CH + (k0+64) + scol, &As[cur^1][p*4096 + w*512]);
      #pragma unroll
      for (int p = 0; p < 3; ++p)
        gload_lds16(Bb + (size_t)(p*64 + srow)*CH + (k0+64) + scol, &Bs[cur^1][p*4096 + w*512]);
    }
    #pragma unroll
    for (int kk = 0; kk < 2; ++kk) {
      bf16x8 af[8], bfr[3];
      #pragma unroll
      for (int m = 0; m < 8; ++m)
        af[m] = *(const bf16x8*)&As[cur][(wm*128 + m*16 + qi)*64 + kk*32 + g*8];
      #pragma unroll
      for (int n = 0; n < 3; ++n)
        bfr[n] = *(const bf16x8*)&Bs[cur][(wn*48 + n*16 + qi)*64 + kk*32 + g*8];
      #pragma unroll
      for (int m = 0; m < 8; ++m)
        #pragma unroll
        for (int n = 0; n < 3; ++n)
          acc[m][n] = __builtin_amdgcn_mfma_f32_16x16x32_bf16(af[m], bfr[n], acc[m][n], 0, 0, 0);
    }
    __syncthreads();   // drains prefetch + guards buffer reuse
    cur ^= 1;
  }

  // epilogue: scatter to q/k [bh][t][64] and v^T [bh][64][t]
  #pragma unroll
  for (int m = 0; m < 8; ++m) {
    const int row0 = bm*256 + wm*128 + m*16 + g*4;
    const int bb = row0 >> 11;          // batch (4-row group never crosses)
    const int t0 = row0 & 2047;
    #pragma unroll
    for (int n = 0; n < 3; ++n) {
      const int col = bn*192 + wn*48 + n*16 + qi;   // fragment never straddles 1024
      const float bv = bias[col];
      const int which = col >> 10;      // 0=q 1=k 2=v
      const int cc = col & 1023;
      const int h = cc >> 6, d = cc & 63;
      const int bh = bb*16 + h;
      if (which == 2) {
        ushort4 pw;
        pw.x = f2b(acc[m][n][0] + bv);
        pw.y = f2b(acc[m][n][1] + bv);
        pw.z = f2b(acc[m][n][2] + bv);
        pw.w = f2b(acc[m][n][3] + bv);
        *(ushort4*)&vtb[((size_t)bh*HDIM + d)*SEQ + t0] = pw;
      } else {
        u16* dst = (which == 0) ? qbo : kb;
        #pragma unroll
        for (int r = 0; r < 4; ++r)
          dst[((size_t)bh*SEQ + t0 + r)*HDIM + d] = f2b(acc[m][n][r] + bv);
      }
    }
  }
}

// ---------- proj GEMM: out[4096][1024] f32 = y[4096][1024] * wpt^T + b ----------
// 128x128 tile, 2-phase dbuf, plain block mapping (grid 8x32 = 256 = 1/CU).
__global__ __launch_bounds__(256) void csa_gemm_proj(
    const u16* __restrict__ A, const u16* __restrict__ Bt,
    const float* __restrict__ bias, float* __restrict__ out)
{
  __shared__ __align__(16) u16 As[2][128*64];
  __shared__ __align__(16) u16 Bs[2][128*64];
  const int t = threadIdx.x, lane = t & 63, w = t >> 6;
  const int wm = w >> 1, wn = w & 1, g = lane >> 4, qi = lane & 15;
  const int bm = blockIdx.y, bn = blockIdx.x;

  f32x4 acc[4][4] = {};

  const u16* Ab = A  + (size_t)(bm*128)*CH;
  const u16* Bb = Bt + (size_t)(bn*128)*CH;
  const int srow = t >> 3;
  const int scol = (t & 7) * 8;

  #pragma unroll
  for (int p = 0; p < 4; ++p) {
    gload_lds16(Ab + (size_t)(p*32 + srow)*CH + scol, &As[0][p*2048 + w*512]);
    gload_lds16(Bb + (size_t)(p*32 + srow)*CH + scol, &Bs[0][p*2048 + w*512]);
  }
  __syncthreads();

  int cur = 0;
  for (int k0 = 0; k0 < CH; k0 += 64) {
    if (k0 + 64 < CH) {
      #pragma unroll
      for (int p = 0; p < 4; ++p) {
        gload_lds16(Ab + (size_t)(p*32 + srow)*CH + (k0+64) + scol, &As[cur^1][p*2048 + w*512]);
        gload_lds16(Bb + (size_t)(p*32 + srow)*CH + (k0+64) + scol, &Bs[cur^1][p*2048 + w*512]);
      }
    }
    #pragma unroll
    for (int kk = 0; kk < 2; ++kk) {
      bf16x8 af[4], bfr[4];
      #pragma unroll
      for (int m = 0; m < 4; ++m)
        af[m] = *(const bf16x8*)&As[cur][(wm*64 + m*16 + qi)*64 + kk*32 + g*8];
      #pragma unroll
      for (int n = 0; n < 4; ++n)
        bfr[n] = *(const bf16x8*)&Bs[cur][(wn*64 + n*16 + qi)*64 + kk*32 + g*8];
      #pragma unroll
      for (int m = 0; m < 4; ++m)
        #pragma unroll
        for (int n = 0; n < 4; ++n)
          acc[m][n] = __builtin_amdgcn_mfma_f32_16x16x32_bf16(af[m], bfr[n], acc[m][n], 0, 0, 0);
    }
    __syncthreads();
    cur ^= 1;
  }

  #pragma unroll
  for (int m = 0; m < 4; ++m) {
    const int row0 = bm*128 + wm*64 + m*16 + g*4;
    #pragma unroll
    for (int n = 0; n < 4; ++n) {
      const int col = bn*128 + wn*64 + n*16 + qi;
      const float bv = bias[col];
      #pragma unroll
      for (int r = 0; r < 4; ++r)
        out[(size_t)(row0 + r)*CH + col] = acc[m][n][r] + bv;
    }
  }
}

// ---------- causal flash attention v3 ----------
// grid: x = bh (32), y = pair (8). Block = 8 waves (512 thr), q-tile 128 rows,
// 16 q-rows per wave; processes q-tiles {p, 15-p} -> uniform 36 kt-iterations.
// One 64x64 K/V stage serves 128 q rows (2x amortization vs v2). Per-wave
// early-exit guard (kt <= qrow>>6) skips fully-masked diagonal tiles while
// keeping barriers block-uniform. Double-buffered K/V, single barrier/iter.
__global__ __launch_bounds__(512) void csa_attn(
    const u16* __restrict__ qb, const u16* __restrict__ kb,
    const u16* __restrict__ vtb, u16* __restrict__ yout)
{
  const int bh = blockIdx.x, pair = blockIdx.y;
  const int bidx = bh >> 4, h = bh & 15;
  const int t = threadIdx.x, lane = t & 63, w = t >> 6;   // w 0..7
  const int g = lane >> 4, qi = lane & 15;
  __shared__ __align__(16) u16 Ks[2][64*64];
  __shared__ __align__(16) u16 Vs[2][64*64];    // V^T tile: [d][key]
  __shared__ __align__(16) u16 Ps[8][16*64];    // per-wave P [q][key] (no barrier)

  const size_t kvbase = (size_t)bh * SEQ * HDIM;   // == bh*HDIM*SEQ for vtb
  const int srow = t >> 3;               // 0..63: full 64-row tile in one pass
  const int ssw  = (srow & 7) * 8;
  const int scol = ((t & 7) * 8) ^ ssw;  // pre-swizzled source column

  int offK[2][4], offPw[4], offPr[2];
  #pragma unroll
  for (int c = 0; c < 2; ++c) {
    offPr[c] = SWZ(qi, c*32 + g*8);
    #pragma unroll
    for (int s4 = 0; s4 < 4; ++s4) offK[c][s4] = SWZ(s4*16 + qi, c*32 + g*8);
  }
  #pragma unroll
  for (int s4 = 0; s4 < 4; ++s4) offPw[s4] = SWZ(qi, s4*16 + g*4);

  const float QSCALE = 0.18033688011112042f;   // 0.125 * log2(e)

  for (int half = 0; half < 2; ++half) {
    const int qt = half ? (15 - pair) : pair;
    const int qrow = qt*128 + w*16;
    const int nkt = 2*qt + 2;
    const int kend = qrow >> 6;          // wave's last key-tile (diagonal)

    // Q fragment, pre-scaled by 0.125*log2e (exp2-domain softmax)
    bf16x8 qf[2];
    #pragma unroll
    for (int c = 0; c < 2; ++c) {
      qf[c] = *(const bf16x8*)&qb[(kvbase + (size_t)(qrow + qi)*HDIM) + c*32 + g*8];
      #pragma unroll
      for (int e = 0; e < 8; ++e)
        qf[c][e] = (short)f2b(b2f((u16)qf[c][e]) * QSCALE);
    }

    f32x4 yacc[4] = {};
    float mrun = -1e30f, srun = 0.f;

    // prologue: stage kt=0 into buf 0 (one gload per thread per tile)
    gload_lds16(kb  + kvbase + (size_t)srow*HDIM + scol, &Ks[0][w*512]);
    gload_lds16(vtb + kvbase + (size_t)srow*SEQ  + scol, &Vs[0][w*512]);
    __syncthreads();

    int cur = 0;
    for (int kt = 0; kt < nkt; ++kt) {
      // prefetch kt+1 into buf^1 (flies under compute; drained at barrier)
      if (kt + 1 < nkt) {
        const int k1 = (kt + 1) * 64;
        gload_lds16(kb  + kvbase + (size_t)(k1 + srow)*HDIM + scol, &Ks[cur^1][w*512]);
        gload_lds16(vtb + kvbase + (size_t)srow*SEQ + k1 + scol,    &Vs[cur^1][w*512]);
      }

      if (kt <= kend) {   // wave-uniform guard: skip fully-masked tiles
        // S^T = K * Q^T
        f32x4 st[4] = {};
        #pragma unroll
        for (int c = 0; c < 2; ++c)
          #pragma unroll
          for (int s4 = 0; s4 < 4; ++s4) {
            bf16x8 kf = *(const bf16x8*)&Ks[cur][offK[c][s4]];
            st[s4] = __builtin_amdgcn_mfma_f32_16x16x32_bf16(kf, qf[c], st[s4], 0, 0, 0);
          }

        // diagonal-tile causal mask (per-lane q = qrow + qi)
        if (kt == kend) {
          const int lq = (qrow & 63) + qi;
          #pragma unroll
          for (int s4 = 0; s4 < 4; ++s4)
            #pragma unroll
            for (int r = 0; r < 4; ++r)
              if (s4*16 + g*4 + r > lq) st[s4][r] = -3.0e38f;
        }

        // online softmax (exp2 domain), defer-max
        float tmax = st[0][0];
        #pragma unroll
        for (int s4 = 0; s4 < 4; ++s4)
          #pragma unroll
          for (int r = 0; r < 4; ++r) tmax = fmaxf(tmax, st[s4][r]);
        tmax = fmaxf(tmax, __shfl_xor(tmax, 16));
        tmax = fmaxf(tmax, __shfl_xor(tmax, 32));
        if (!__all(tmax - mrun <= 11.5f)) {
          float mnew = fmaxf(mrun, tmax);
          float fac = exp2_fast(mrun - mnew);
          #pragma unroll
          for (int r = 0; r < 4; ++r) {
            float fr = __shfl(fac, g*4 + r);
            #pragma unroll
            for (int nf = 0; nf < 4; ++nf) yacc[nf][r] *= fr;
          }
          srun *= fac;
          mrun = mnew;
        }
        float tsum = 0.f;
        #pragma unroll
        for (int s4 = 0; s4 < 4; ++s4)
          #pragma unroll
          for (int r = 0; r < 4; ++r) {
            float pv = exp2_fast(st[s4][r] - mrun);
            st[s4][r] = pv;
            tsum += pv;
          }
        tsum += __shfl_xor(tsum, 16);
        tsum += __shfl_xor(tsum, 32);
        srun += tsum;

        // P -> per-wave LDS (bf16 via cvt_pk; same-wave, no barrier)
        #pragma unroll
        for (int s4 = 0; s4 < 4; ++s4) {
          uint2 pw;
          pw.x = cvt_pk_bf16(st[s4][0], st[s4][1]);
          pw.y = cvt_pk_bf16(st[s4][2], st[s4][3]);
          *(uint2*)&Ps[w][offPw[s4]] = pw;
        }

        // O += P * V
        #pragma unroll
        for (int c = 0; c < 2; ++c) {
          bf16x8 pa = *(const bf16x8*)&Ps[w][offPr[c]];
          #pragma unroll
          for (int nf = 0; nf < 4; ++nf) {
            bf16x8 vf = *(const bf16x8*)&Vs[cur][offK[c][nf]];
            yacc[nf] = __builtin_amdgcn_mfma_f32_16x16x32_bf16(pa, vf, yacc[nf], 0, 0, 0);
          }
        }
      }

      __syncthreads();   // drains prefetch (vmcnt) + guards buf reuse
      cur ^= 1;
    }

    // epilogue for this tile
    #pragma unroll
    for (int r = 0; r < 4; ++r) {
      float sv = __shfl(srun, g*4 + r);
      float inv = 1.f / sv;
      int qg = qrow + g*4 + r;
      #pragma unroll
      for (int nf = 0; nf < 4; ++nf) {
        int d = nf*16 + qi;
        yout[((size_t)bidx*SEQ + qg)*CH + h*HDIM + d] = f2b(yacc[nf][r] * inv);
      }
    }
  }
}

extern "C" void kernel_launch(void* const* d_in, const int* in_sizes, int n_in,
                              void* d_out, int out_size, void* d_ws, size_t ws_size,
                              hipStream_t stream) {
  (void)in_sizes; (void)n_in; (void)out_size; (void)ws_size;
  const float* x      = (const float*)d_in[0];
  const float* w_attn = (const float*)d_in[1];
  const float* b_attn = (const float*)d_in[2];
  const float* w_proj = (const float*)d_in[3];
  const float* b_proj = (const float*)d_in[4];

  char* ws = (char*)d_ws;
  const size_t MB = 1024*1024;
  u16* xb  = (u16*)(ws);             // 8 MB, reused as attention out y
  u16* wat = (u16*)(ws +  8*MB);     // 6 MB  w_attn^T [3072][1024]
  u16* wpt = (u16*)(ws + 14*MB);     // 2 MB  w_proj^T [1024][1024]
  u16* qb  = (u16*)(ws + 16*MB);     // 8 MB  [bh][t][64]
  u16* kb  = (u16*)(ws + 24*MB);     // 8 MB  [bh][t][64]
  u16* vtb = (u16*)(ws + 32*MB);     // 8 MB  [bh][64][t]

  csa_convert_x<<<2048, 256, 0, stream>>>(x, xb, ROWS*CH/8);
  csa_transpose2<<<dim3(128, 32), dim3(32, 8), 0, stream>>>(w_attn, w_proj, wat, wpt);
  csa_gemm_qkv<<<dim3(16, 16), 512, 0, stream>>>(xb, wat, b_attn, qb, kb, vtb);
  csa_attn<<<dim3(32, 8), 512, 0, stream>>>(qb, kb, vtb, xb);
  csa_gemm_proj<<<dim3(8, 32), 256, 0, stream>>>(xb, wpt, b_proj, (float*)d_out);
}

// Round 7
// 119.425 us; speedup vs baseline: 1.0022x; 1.0022x over previous
//
#include <hip/hip_runtime.h>

typedef unsigned short u16;
typedef short bf16x8 __attribute__((ext_vector_type(8)));
typedef float f32x4 __attribute__((ext_vector_type(4)));

#define BATCH 2
#define SEQ   2048
#define CH    1024
#define NHEAD 16
#define HDIM  64
#define ROWS  (BATCH*SEQ)   // 4096

// swizzled LDS index for [*][64] bf16 tiles: breaks 128B-row bank conflicts
#define SWZ(r_, c_) (((r_)*64) + ((c_) ^ (((r_)&7)*8)))

__device__ __forceinline__ u16 f2b(float f) {
  unsigned u = __builtin_bit_cast(unsigned, f);
  u += 0x7FFFu + ((u >> 16) & 1u);
  return (u16)(u >> 16);
}
__device__ __forceinline__ float b2f(u16 h) {
  unsigned u = ((unsigned)h) << 16;
  return __builtin_bit_cast(float, u);
}
__device__ __forceinline__ float exp2_fast(float x) {
  float r; asm("v_exp_f32 %0, %1" : "=v"(r) : "v"(x)); return r;
}
__device__ __forceinline__ unsigned cvt_pk_bf16(float a, float b) {
  unsigned r; asm("v_cvt_pk_bf16_f32 %0, %1, %2" : "=v"(r) : "v"(a), "v"(b)); return r;
}

__device__ __forceinline__ void gload_lds16(const void* g, void* l) {
  __builtin_amdgcn_global_load_lds(
      (const __attribute__((address_space(1))) unsigned int*)g,
      (__attribute__((address_space(3))) unsigned int*)l, 16, 0, 0);
}

// ---------- x (f32) -> bf16 [4096][1024] ----------
__global__ void csa_convert_x(const float* __restrict__ in, u16* __restrict__ out,
                              int n8) {
  int i = blockIdx.x * 256 + threadIdx.x;
  if (i >= n8) return;
  const float4* f4 = (const float4*)in;
  float4 v0 = f4[2*i], v1 = f4[2*i+1];
  ushort4 o0, o1;
  o0.x = f2b(v0.x); o0.y = f2b(v0.y); o0.z = f2b(v0.z); o0.w = f2b(v0.w);
  o1.x = f2b(v1.x); o1.y = f2b(v1.y); o1.z = f2b(v1.z); o1.w = f2b(v1.w);
  ((ushort4*)out)[2*i]   = o0;
  ((ushort4*)out)[2*i+1] = o1;
}

// ---------- both weights [1024][C] f32 -> Wt [C][1024] bf16, one launch ----------
__global__ void csa_transpose2(const float* __restrict__ wa, const float* __restrict__ wp,
                               u16* __restrict__ wat, u16* __restrict__ wpt) {
  __shared__ float tile[32][33];
  int bx = blockIdx.x;
  const float* in; u16* out; int C;
  if (bx < 96) { in = wa; out = wat; C = 3*CH; }
  else         { in = wp; out = wpt; C = CH; bx -= 96; }
  const int R = CH;
  const int bxc = bx * 32, by = blockIdx.y * 32;
  const int tx = threadIdx.x, ty = threadIdx.y;
  #pragma unroll
  for (int j = 0; j < 4; ++j) {
    int r = by + ty + j*8, c = bxc + tx;
    tile[ty + j*8][tx] = in[(size_t)r*C + c];
  }
  __syncthreads();
  #pragma unroll
  for (int j = 0; j < 4; ++j) {
    int oc = bxc + ty + j*8;   // column of in = row of out
    int orr = by + tx;         // row of in   = col of out
    out[(size_t)oc*R + orr] = f2b(tile[tx][ty + j*8]);
  }
}

// ---------- QKV GEMM: [4096][3072] = xb[4096][1024] * wat[3072][1024]^T + b ----
// BM=256, BN=192, BK=64; 512 thr = 8 waves (2M x 4N), per-wave 128x48.
// Grid 16x16 = 256 blocks = exactly 1/CU. 2-phase single-barrier dbuf.
// 2D-chunk XCD swizzle: each XCD gets a 4bm x 8bn region (~5MB footprint).
__global__ __launch_bounds__(512) void csa_gemm_qkv(
    const u16* __restrict__ A, const u16* __restrict__ Bt,
    const float* __restrict__ bias,
    u16* __restrict__ qbo, u16* __restrict__ kb, u16* __restrict__ vtb)
{
  __shared__ __align__(16) u16 As[2][256*64];   // 64 KB
  __shared__ __align__(16) u16 Bs[2][192*64];   // 48 KB
  const int t = threadIdx.x, lane = t & 63, w = t >> 6;
  const int wm = w >> 2, wn = w & 3, g = lane >> 4, qi = lane & 15;

  // bijective 2D-chunk swizzle over the 16x16 grid (8 chunks of 4bm x 8bn)
  const int wgid = blockIdx.y * 16 + blockIdx.x;
  const int c8 = wgid & 7, inner = wgid >> 3;
  const int bm = (c8 >> 1) * 4 + (inner >> 3);   // 0..15
  const int bn = (c8 & 1) * 8 + (inner & 7);     // 0..15

  f32x4 acc[8][3] = {};

  const u16* Ab = A  + (size_t)(bm*256)*CH;
  const u16* Bb = Bt + (size_t)(bn*192)*CH;
  const int srow = t >> 3;          // 0..63
  const int scol = (t & 7) * 8;

  // prologue: stage k0=0 into buf 0
  #pragma unroll
  for (int p = 0; p < 4; ++p)
    gload_lds16(Ab + (size_t)(p*64 + srow)*CH + scol, &As[0][p*4096 + w*512]);
  #pragma unroll
  for (int p = 0; p < 3; ++p)
    gload_lds16(Bb + (size_t)(p*64 + srow)*CH + scol, &Bs[0][p*4096 + w*512]);
  __syncthreads();

  int cur = 0;
  for (int k0 = 0; k0 < CH; k0 += 64) {
    if (k0 + 64 < CH) {   // prefetch next K-tile into buf^1
      #pragma unroll
      for (int p = 0; p < 4; ++p)
        gload_lds16(Ab + (size_t)(p*64 + srow)*CH + (k0+64) + scol, &As[cur^1][p*4096 + w*512]);
      #pragma unroll
      for (int p = 0; p < 3; ++p)
        gload_lds16(Bb + (size_t)(p*64 + srow)*CH + (k0+64) + scol, &Bs[cur^1][p*4096 + w*512]);
    }
    #pragma unroll
    for (int kk = 0; kk < 2; ++kk) {
      bf16x8 af[8], bfr[3];
      #pragma unroll
      for (int m = 0; m < 8; ++m)
        af[m] = *(const bf16x8*)&As[cur][(wm*128 + m*16 + qi)*64 + kk*32 + g*8];
      #pragma unroll
      for (int n = 0; n < 3; ++n)
        bfr[n] = *(const bf16x8*)&Bs[cur][(wn*48 + n*16 + qi)*64 + kk*32 + g*8];
      #pragma unroll
      for (int m = 0; m < 8; ++m)
        #pragma unroll
        for (int n = 0; n < 3; ++n)
          acc[m][n] = __builtin_amdgcn_mfma_f32_16x16x32_bf16(af[m], bfr[n], acc[m][n], 0, 0, 0);
    }
    __syncthreads();   // drains prefetch + guards buffer reuse
    cur ^= 1;
  }

  // epilogue: scatter to q/k [bh][t][64] and v^T [bh][64][t]
  #pragma unroll
  for (int m = 0; m < 8; ++m) {
    const int row0 = bm*256 + wm*128 + m*16 + g*4;
    const int bb = row0 >> 11;          // batch (4-row group never crosses)
    const int t0 = row0 & 2047;
    #pragma unroll
    for (int n = 0; n < 3; ++n) {
      const int col = bn*192 + wn*48 + n*16 + qi;   // fragment never straddles 1024
      const float bv = bias[col];
      const int which = col >> 10;      // 0=q 1=k 2=v
      const int cc = col & 1023;
      const int h = cc >> 6, d = cc & 63;
      const int bh = bb*16 + h;
      if (which == 2) {
        ushort4 pw;
        pw.x = f2b(acc[m][n][0] + bv);
        pw.y = f2b(acc[m][n][1] + bv);
        pw.z = f2b(acc[m][n][2] + bv);
        pw.w = f2b(acc[m][n][3] + bv);
        *(ushort4*)&vtb[((size_t)bh*HDIM + d)*SEQ + t0] = pw;
      } else {
        u16* dst = (which == 0) ? qbo : kb;
        #pragma unroll
        for (int r = 0; r < 4; ++r)
          dst[((size_t)bh*SEQ + t0 + r)*HDIM + d] = f2b(acc[m][n][r] + bv);
      }
    }
  }
}

// ---------- proj GEMM: out[4096][1024] f32 = y[4096][1024] * wpt^T + b ----------
// 128x128 tile, 2-phase dbuf, plain block mapping (grid 8x32 = 256 = 1/CU).
__global__ __launch_bounds__(256) void csa_gemm_proj(
    const u16* __restrict__ A, const u16* __restrict__ Bt,
    const float* __restrict__ bias, float* __restrict__ out)
{
  __shared__ __align__(16) u16 As[2][128*64];
  __shared__ __align__(16) u16 Bs[2][128*64];
  const int t = threadIdx.x, lane = t & 63, w = t >> 6;
  const int wm = w >> 1, wn = w & 1, g = lane >> 4, qi = lane & 15;
  const int bm = blockIdx.y, bn = blockIdx.x;

  f32x4 acc[4][4] = {};

  const u16* Ab = A  + (size_t)(bm*128)*CH;
  const u16* Bb = Bt + (size_t)(bn*128)*CH;
  const int srow = t >> 3;
  const int scol = (t & 7) * 8;

  #pragma unroll
  for (int p = 0; p < 4; ++p) {
    gload_lds16(Ab + (size_t)(p*32 + srow)*CH + scol, &As[0][p*2048 + w*512]);
    gload_lds16(Bb + (size_t)(p*32 + srow)*CH + scol, &Bs[0][p*2048 + w*512]);
  }
  __syncthreads();

  int cur = 0;
  for (int k0 = 0; k0 < CH; k0 += 64) {
    if (k0 + 64 < CH) {
      #pragma unroll
      for (int p = 0; p < 4; ++p) {
        gload_lds16(Ab + (size_t)(p*32 + srow)*CH + (k0+64) + scol, &As[cur^1][p*2048 + w*512]);
        gload_lds16(Bb + (size_t)(p*32 + srow)*CH + (k0+64) + scol, &Bs[cur^1][p*2048 + w*512]);
      }
    }
    #pragma unroll
    for (int kk = 0; kk < 2; ++kk) {
      bf16x8 af[4], bfr[4];
      #pragma unroll
      for (int m = 0; m < 4; ++m)
        af[m] = *(const bf16x8*)&As[cur][(wm*64 + m*16 + qi)*64 + kk*32 + g*8];
      #pragma unroll
      for (int n = 0; n < 4; ++n)
        bfr[n] = *(const bf16x8*)&Bs[cur][(wn*64 + n*16 + qi)*64 + kk*32 + g*8];
      #pragma unroll
      for (int m = 0; m < 4; ++m)
        #pragma unroll
        for (int n = 0; n < 4; ++n)
          acc[m][n] = __builtin_amdgcn_mfma_f32_16x16x32_bf16(af[m], bfr[n], acc[m][n], 0, 0, 0);
    }
    __syncthreads();
    cur ^= 1;
  }

  #pragma unroll
  for (int m = 0; m < 4; ++m) {
    const int row0 = bm*128 + wm*64 + m*16 + g*4;
    #pragma unroll
    for (int n = 0; n < 4; ++n) {
      const int col = bn*128 + wn*64 + n*16 + qi;
      const float bv = bias[col];
      #pragma unroll
      for (int r = 0; r < 4; ++r)
        out[(size_t)(row0 + r)*CH + col] = acc[m][n][r] + bv;
    }
  }
}

// ---------- causal flash attention v4 ----------
// grid 32 x 8, 512 thr (8 waves x 16 q-rows), q-tile 128, pairs {p, 15-p}.
// 2-deep pipeline: iteration kt computes QK^T(kt+1) (independent MFMA,
// interleaves with softmax(kt) VALU) then softmax(kt)+PV(kt). K double-buffer,
// V TRIPLE-buffer (stage kt+2 must not overwrite V[kt] being read this iter).
// Shfl-free online softmax: mrun/srun are per-lane partials; __all() over
// partial maxes == full-row defer-max check; cross-lane reduces only in the
// rare rescale branch and at the epilogue.
__global__ __launch_bounds__(512) void csa_attn(
    const u16* __restrict__ qb, const u16* __restrict__ kb,
    const u16* __restrict__ vtb, u16* __restrict__ yout)
{
  const int bh = blockIdx.x, pair = blockIdx.y;
  const int bidx = bh >> 4, h = bh & 15;
  const int t = threadIdx.x, lane = t & 63, w = t >> 6;   // w 0..7
  const int g = lane >> 4, qi = lane & 15;
  __shared__ __align__(16) u16 Ks[2][64*64];    // 16 KB
  __shared__ __align__(16) u16 Vs[3][64*64];    // 24 KB, V^T tiles [d][key]
  __shared__ __align__(16) u16 Ps[8][16*64];    // 16 KB, per-wave P [q][key]

  const size_t kvbase = (size_t)bh * SEQ * HDIM;   // == bh*HDIM*SEQ for vtb
  const int srow = t >> 3;               // 0..63: full 64-row tile in one pass
  const int ssw  = (srow & 7) * 8;
  const int scol = ((t & 7) * 8) ^ ssw;  // pre-swizzled source column

  int offK[2][4], offPw[4], offPr[2];
  #pragma unroll
  for (int c = 0; c < 2; ++c) {
    offPr[c] = SWZ(qi, c*32 + g*8);
    #pragma unroll
    for (int s4 = 0; s4 < 4; ++s4) offK[c][s4] = SWZ(s4*16 + qi, c*32 + g*8);
  }
  #pragma unroll
  for (int s4 = 0; s4 < 4; ++s4) offPw[s4] = SWZ(qi, s4*16 + g*4);

  const float QSCALE = 0.18033688011112042f;   // 0.125 * log2(e)

  for (int half = 0; half < 2; ++half) {
    const int qt = half ? (15 - pair) : pair;
    const int qrow = qt*128 + w*16;
    const int nkt = 2*qt + 2;
    const int kend = qrow >> 6;          // wave's last (diagonal) key-tile

    // Q fragment, pre-scaled by 0.125*log2e (exp2-domain softmax)
    bf16x8 qf[2];
    #pragma unroll
    for (int c = 0; c < 2; ++c) {
      qf[c] = *(const bf16x8*)&qb[(kvbase + (size_t)(qrow + qi)*HDIM) + c*32 + g*8];
      #pragma unroll
      for (int e = 0; e < 8; ++e)
        qf[c][e] = (short)f2b(b2f((u16)qf[c][e]) * QSCALE);
    }

    f32x4 yacc[4] = {};
    float mrun = -1e30f, srun = 0.f;     // per-lane partials (row = qi)

    // prologue: stage tile 0, barrier, QK(0), then launch stage of tile 1
    gload_lds16(kb  + kvbase + (size_t)srow*HDIM + scol, &Ks[0][w*512]);
    gload_lds16(vtb + kvbase + (size_t)srow*SEQ  + scol, &Vs[0][w*512]);
    __syncthreads();
    if (nkt > 1) {
      gload_lds16(kb  + kvbase + (size_t)(64 + srow)*HDIM + scol, &Ks[1][w*512]);
      gload_lds16(vtb + kvbase + (size_t)srow*SEQ + 64 + scol,    &Vs[1][w*512]);
    }
    f32x4 st[4] = {};
    #pragma unroll
    for (int c = 0; c < 2; ++c)
      #pragma unroll
      for (int s4 = 0; s4 < 4; ++s4) {
        bf16x8 kf = *(const bf16x8*)&Ks[0][offK[c][s4]];
        st[s4] = __builtin_amdgcn_mfma_f32_16x16x32_bf16(kf, qf[c], st[s4], 0, 0, 0);
      }

    int v0i = 0, v2i = 2;                // V buffer of kt, and of kt+2
    for (int kt = 0; kt < nkt; ++kt) {
      __syncthreads();                   // stage(kt+1) landed; old reads done

      // stage tile kt+2 (targets: Ks[kt&1]=dead K[kt], Vs[v2i]=dead V[kt-1])
      if (kt + 2 < nkt) {
        const int k2 = (kt + 2) * 64;
        gload_lds16(kb  + kvbase + (size_t)(k2 + srow)*HDIM + scol, &Ks[kt & 1][w*512]);
        gload_lds16(vtb + kvbase + (size_t)srow*SEQ + k2 + scol,    &Vs[v2i][w*512]);
      }

      // QK^T(kt+1) from Ks[(kt+1)&1] — independent of softmax(kt) below
      f32x4 st2[4] = {};
      const bool doqk = (kt + 1 <= kend);
      if (doqk) {
        #pragma unroll
        for (int c = 0; c < 2; ++c)
          #pragma unroll
          for (int s4 = 0; s4 < 4; ++s4) {
            bf16x8 kf = *(const bf16x8*)&Ks[(kt + 1) & 1][offK[c][s4]];
            st2[s4] = __builtin_amdgcn_mfma_f32_16x16x32_bf16(kf, qf[c], st2[s4], 0, 0, 0);
          }
      }

      if (kt <= kend) {
        // diagonal-tile causal mask
        if (kt == kend) {
          const int lq = (qrow & 63) + qi;
          #pragma unroll
          for (int s4 = 0; s4 < 4; ++s4)
            #pragma unroll
            for (int r = 0; r < 4; ++r)
              if (s4*16 + g*4 + r > lq) st[s4][r] = -3.0e38f;
        }

        // per-lane partial max (max3-friendly chains)
        float m0 = fmaxf(fmaxf(fmaxf(st[0][0], st[0][1]), st[0][2]), st[0][3]);
        float m1 = fmaxf(fmaxf(fmaxf(st[1][0], st[1][1]), st[1][2]), st[1][3]);
        float m2 = fmaxf(fmaxf(fmaxf(st[2][0], st[2][1]), st[2][2]), st[2][3]);
        float m3 = fmaxf(fmaxf(fmaxf(st[3][0], st[3][1]), st[3][2]), st[3][3]);
        float tmax = fmaxf(fmaxf(fmaxf(m0, m1), m2), m3);

        if (!__all(tmax - mrun <= 11.5f)) {   // rare: true rescale
          float tmf = fmaxf(tmax, __shfl_xor(tmax, 16));
          tmf = fmaxf(tmf, __shfl_xor(tmf, 32));
          float mnew = fmaxf(mrun, tmf);
          float fac = exp2_fast(mrun - mnew);
          #pragma unroll
          for (int r = 0; r < 4; ++r) {
            float fr = __shfl(fac, g*4 + r);
            #pragma unroll
            for (int nf = 0; nf < 4; ++nf) yacc[nf][r] *= fr;
          }
          srun *= fac;
          mrun = mnew;
        }
        float tsum = 0.f;
        #pragma unroll
        for (int s4 = 0; s4 < 4; ++s4)
          #pragma unroll
          for (int r = 0; r < 4; ++r) {
            float pv = exp2_fast(st[s4][r] - mrun);
            st[s4][r] = pv;
            tsum += pv;
          }
        srun += tsum;                    // per-lane partial; reduced at epilogue

        // P -> per-wave LDS (bf16 via cvt_pk; same-wave, no barrier)
        #pragma unroll
        for (int s4 = 0; s4 < 4; ++s4) {
          uint2 pw;
          pw.x = cvt_pk_bf16(st[s4][0], st[s4][1]);
          pw.y = cvt_pk_bf16(st[s4][2], st[s4][3]);
          *(uint2*)&Ps[w][offPw[s4]] = pw;
        }

        // O += P * V
        __builtin_amdgcn_s_setprio(1);
        #pragma unroll
        for (int c = 0; c < 2; ++c) {
          bf16x8 pa = *(const bf16x8*)&Ps[w][offPr[c]];
          #pragma unroll
          for (int nf = 0; nf < 4; ++nf) {
            bf16x8 vf = *(const bf16x8*)&Vs[v0i][offK[c][nf]];
            yacc[nf] = __builtin_amdgcn_mfma_f32_16x16x32_bf16(pa, vf, yacc[nf], 0, 0, 0);
          }
        }
        __builtin_amdgcn_s_setprio(0);
      }

      // rotate pipeline state
      if (doqk) {
        #pragma unroll
        for (int s4 = 0; s4 < 4; ++s4) st[s4] = st2[s4];
      }
      v0i = (v0i == 2) ? 0 : v0i + 1;
      v2i = (v2i == 2) ? 0 : v2i + 1;
    }

    // epilogue: reduce per-lane partial sums across the 4 g-groups
    float srf = srun + __shfl_xor(srun, 16);
    srf += __shfl_xor(srf, 32);
    #pragma unroll
    for (int r = 0; r < 4; ++r) {
      float sv = __shfl(srf, g*4 + r);
      float inv = 1.f / sv;
      int qg = qrow + g*4 + r;
      #pragma unroll
      for (int nf = 0; nf < 4; ++nf) {
        int d = nf*16 + qi;
        yout[((size_t)bidx*SEQ + qg)*CH + h*HDIM + d] = f2b(yacc[nf][r] * inv);
      }
    }
  }
}

extern "C" void kernel_launch(void* const* d_in, const int* in_sizes, int n_in,
                              void* d_out, int out_size, void* d_ws, size_t ws_size,
                              hipStream_t stream) {
  (void)in_sizes; (void)n_in; (void)out_size; (void)ws_size;
  const float* x      = (const float*)d_in[0];
  const float* w_attn = (const float*)d_in[1];
  const float* b_attn = (const float*)d_in[2];
  const float* w_proj = (const float*)d_in[3];
  const float* b_proj = (const float*)d_in[4];

  char* ws = (char*)d_ws;
  const size_t MB = 1024*1024;
  u16* xb  = (u16*)(ws);             // 8 MB, reused as attention out y
  u16* wat = (u16*)(ws +  8*MB);     // 6 MB  w_attn^T [3072][1024]
  u16* wpt = (u16*)(ws + 14*MB);     // 2 MB  w_proj^T [1024][1024]
  u16* qb  = (u16*)(ws + 16*MB);     // 8 MB  [bh][t][64]
  u16* kb  = (u16*)(ws + 24*MB);     // 8 MB  [bh][t][64]
  u16* vtb = (u16*)(ws + 32*MB);     // 8 MB  [bh][64][t]

  csa_convert_x<<<2048, 256, 0, stream>>>(x, xb, ROWS*CH/8);
  csa_transpose2<<<dim3(128, 32), dim3(32, 8), 0, stream>>>(w_attn, w_proj, wat, wpt);
  csa_gemm_qkv<<<dim3(16, 16), 512, 0, stream>>>(xb, wat, b_attn, qb, kb, vtb);
  csa_attn<<<dim3(32, 8), 512, 0, stream>>>(qb, kb, vtb, xb);
  csa_gemm_proj<<<dim3(8, 32), 256, 0, stream>>>(xb, wpt, b_proj, (float*)d_out);
}

// Round 8
// 110.893 us; speedup vs baseline: 1.0793x; 1.0769x over previous
//
#include <hip/hip_runtime.h>

typedef unsigned short u16;
typedef short bf16x8 __attribute__((ext_vector_type(8)));
typedef float f32x4 __attribute__((ext_vector_type(4)));

#define BATCH 2
#define SEQ   2048
#define CH    1024
#define NHEAD 16
#define HDIM  64
#define ROWS  (BATCH*SEQ)   // 4096

// swizzled LDS index for [*][64] bf16 tiles: breaks 128B-row bank conflicts
#define SWZ(r_, c_) (((r_)*64) + ((c_) ^ (((r_)&7)*8)))

__device__ __forceinline__ u16 f2b(float f) {
  unsigned u = __builtin_bit_cast(unsigned, f);
  u += 0x7FFFu + ((u >> 16) & 1u);
  return (u16)(u >> 16);
}
__device__ __forceinline__ float b2f(u16 h) {
  unsigned u = ((unsigned)h) << 16;
  return __builtin_bit_cast(float, u);
}
__device__ __forceinline__ float exp2_fast(float x) {
  float r; asm("v_exp_f32 %0, %1" : "=v"(r) : "v"(x)); return r;
}
__device__ __forceinline__ unsigned cvt_pk_bf16(float a, float b) {
  unsigned r; asm("v_cvt_pk_bf16_f32 %0, %1, %2" : "=v"(r) : "v"(a), "v"(b)); return r;
}

__device__ __forceinline__ void gload_lds16(const void* g, void* l) {
  __builtin_amdgcn_global_load_lds(
      (const __attribute__((address_space(1))) unsigned int*)g,
      (__attribute__((address_space(3))) unsigned int*)l, 16, 0, 0);
}

// ---------- x (f32) -> bf16 [4096][1024] ----------
__global__ void csa_convert_x(const float* __restrict__ in, u16* __restrict__ out,
                              int n8) {
  int i = blockIdx.x * 256 + threadIdx.x;
  if (i >= n8) return;
  const float4* f4 = (const float4*)in;
  float4 v0 = f4[2*i], v1 = f4[2*i+1];
  ushort4 o0, o1;
  o0.x = f2b(v0.x); o0.y = f2b(v0.y); o0.z = f2b(v0.z); o0.w = f2b(v0.w);
  o1.x = f2b(v1.x); o1.y = f2b(v1.y); o1.z = f2b(v1.z); o1.w = f2b(v1.w);
  ((ushort4*)out)[2*i]   = o0;
  ((ushort4*)out)[2*i+1] = o1;
}

// ---------- both weights [1024][C] f32 -> Wt [C][1024] bf16, one launch ----------
__global__ void csa_transpose2(const float* __restrict__ wa, const float* __restrict__ wp,
                               u16* __restrict__ wat, u16* __restrict__ wpt) {
  __shared__ float tile[32][33];
  int bx = blockIdx.x;
  const float* in; u16* out; int C;
  if (bx < 96) { in = wa; out = wat; C = 3*CH; }
  else         { in = wp; out = wpt; C = CH; bx -= 96; }
  const int R = CH;
  const int bxc = bx * 32, by = blockIdx.y * 32;
  const int tx = threadIdx.x, ty = threadIdx.y;
  #pragma unroll
  for (int j = 0; j < 4; ++j) {
    int r = by + ty + j*8, c = bxc + tx;
    tile[ty + j*8][tx] = in[(size_t)r*C + c];
  }
  __syncthreads();
  #pragma unroll
  for (int j = 0; j < 4; ++j) {
    int oc = bxc + ty + j*8;   // column of in = row of out
    int orr = by + tx;         // row of in   = col of out
    out[(size_t)oc*R + orr] = f2b(tile[tx][ty + j*8]);
  }
}

// ---------- QKV GEMM: [4096][3072] = xb[4096][1024] * wat[3072][1024]^T + b ----
// BM=256, BN=192, BK=64; 512 thr = 8 waves (2M x 4N), per-wave 128x48.
// Grid 16x16 = 256 blocks = exactly 1/CU. 2-phase single-barrier dbuf.
// 2D-chunk XCD swizzle: each XCD gets a 4bm x 8bn region (~5MB footprint).
__global__ __launch_bounds__(512) void csa_gemm_qkv(
    const u16* __restrict__ A, const u16* __restrict__ Bt,
    const float* __restrict__ bias,
    u16* __restrict__ qbo, u16* __restrict__ kb, u16* __restrict__ vtb)
{
  __shared__ __align__(16) u16 As[2][256*64];   // 64 KB
  __shared__ __align__(16) u16 Bs[2][192*64];   // 48 KB
  const int t = threadIdx.x, lane = t & 63, w = t >> 6;
  const int wm = w >> 2, wn = w & 3, g = lane >> 4, qi = lane & 15;

  // bijective 2D-chunk swizzle over the 16x16 grid (8 chunks of 4bm x 8bn)
  const int wgid = blockIdx.y * 16 + blockIdx.x;
  const int c8 = wgid & 7, inner = wgid >> 3;
  const int bm = (c8 >> 1) * 4 + (inner >> 3);   // 0..15
  const int bn = (c8 & 1) * 8 + (inner & 7);     // 0..15

  f32x4 acc[8][3] = {};

  const u16* Ab = A  + (size_t)(bm*256)*CH;
  const u16* Bb = Bt + (size_t)(bn*192)*CH;
  const int srow = t >> 3;          // 0..63
  const int scol = (t & 7) * 8;

  // prologue: stage k0=0 into buf 0
  #pragma unroll
  for (int p = 0; p < 4; ++p)
    gload_lds16(Ab + (size_t)(p*64 + srow)*CH + scol, &As[0][p*4096 + w*512]);
  #pragma unroll
  for (int p = 0; p < 3; ++p)
    gload_lds16(Bb + (size_t)(p*64 + srow)*CH + scol, &Bs[0][p*4096 + w*512]);
  __syncthreads();

  int cur = 0;
  for (int k0 = 0; k0 < CH; k0 += 64) {
    if (k0 + 64 < CH) {   // prefetch next K-tile into buf^1
      #pragma unroll
      for (int p = 0; p < 4; ++p)
        gload_lds16(Ab + (size_t)(p*64 + srow)*CH + (k0+64) + scol, &As[cur^1][p*4096 + w*512]);
      #pragma unroll
      for (int p = 0; p < 3; ++p)
        gload_lds16(Bb + (size_t)(p*64 + srow)*CH + (k0+64) + scol, &Bs[cur^1][p*4096 + w*512]);
    }
    #pragma unroll
    for (int kk = 0; kk < 2; ++kk) {
      bf16x8 af[8], bfr[3];
      #pragma unroll
      for (int m = 0; m < 8; ++m)
        af[m] = *(const bf16x8*)&As[cur][(wm*128 + m*16 + qi)*64 + kk*32 + g*8];
      #pragma unroll
      for (int n = 0; n < 3; ++n)
        bfr[n] = *(const bf16x8*)&Bs[cur][(wn*48 + n*16 + qi)*64 + kk*32 + g*8];
      #pragma unroll
      for (int m = 0; m < 8; ++m)
        #pragma unroll
        for (int n = 0; n < 3; ++n)
          acc[m][n] = __builtin_amdgcn_mfma_f32_16x16x32_bf16(af[m], bfr[n], acc[m][n], 0, 0, 0);
    }
    __syncthreads();   // drains prefetch + guards buffer reuse
    cur ^= 1;
  }

  // epilogue: scatter to q/k [bh][t][64] and v^T [bh][64][t]
  #pragma unroll
  for (int m = 0; m < 8; ++m) {
    const int row0 = bm*256 + wm*128 + m*16 + g*4;
    const int bb = row0 >> 11;          // batch (4-row group never crosses)
    const int t0 = row0 & 2047;
    #pragma unroll
    for (int n = 0; n < 3; ++n) {
      const int col = bn*192 + wn*48 + n*16 + qi;   // fragment never straddles 1024
      const float bv = bias[col];
      const int which = col >> 10;      // 0=q 1=k 2=v
      const int cc = col & 1023;
      const int h = cc >> 6, d = cc & 63;
      const int bh = bb*16 + h;
      if (which == 2) {
        ushort4 pw;
        pw.x = f2b(acc[m][n][0] + bv);
        pw.y = f2b(acc[m][n][1] + bv);
        pw.z = f2b(acc[m][n][2] + bv);
        pw.w = f2b(acc[m][n][3] + bv);
        *(ushort4*)&vtb[((size_t)bh*HDIM + d)*SEQ + t0] = pw;
      } else {
        u16* dst = (which == 0) ? qbo : kb;
        #pragma unroll
        for (int r = 0; r < 4; ++r)
          dst[((size_t)bh*SEQ + t0 + r)*HDIM + d] = f2b(acc[m][n][r] + bv);
      }
    }
  }
}

// ---------- proj GEMM: out[4096][1024] f32 = y[4096][1024] * wpt^T + b ----------
// 128x128 tile, 2-phase dbuf, plain block mapping (grid 8x32 = 256 = 1/CU).
__global__ __launch_bounds__(256) void csa_gemm_proj(
    const u16* __restrict__ A, const u16* __restrict__ Bt,
    const float* __restrict__ bias, float* __restrict__ out)
{
  __shared__ __align__(16) u16 As[2][128*64];
  __shared__ __align__(16) u16 Bs[2][128*64];
  const int t = threadIdx.x, lane = t & 63, w = t >> 6;
  const int wm = w >> 1, wn = w & 1, g = lane >> 4, qi = lane & 15;
  const int bm = blockIdx.y, bn = blockIdx.x;

  f32x4 acc[4][4] = {};

  const u16* Ab = A  + (size_t)(bm*128)*CH;
  const u16* Bb = Bt + (size_t)(bn*128)*CH;
  const int srow = t >> 3;
  const int scol = (t & 7) * 8;

  #pragma unroll
  for (int p = 0; p < 4; ++p) {
    gload_lds16(Ab + (size_t)(p*32 + srow)*CH + scol, &As[0][p*2048 + w*512]);
    gload_lds16(Bb + (size_t)(p*32 + srow)*CH + scol, &Bs[0][p*2048 + w*512]);
  }
  __syncthreads();

  int cur = 0;
  for (int k0 = 0; k0 < CH; k0 += 64) {
    if (k0 + 64 < CH) {
      #pragma unroll
      for (int p = 0; p < 4; ++p) {
        gload_lds16(Ab + (size_t)(p*32 + srow)*CH + (k0+64) + scol, &As[cur^1][p*2048 + w*512]);
        gload_lds16(Bb + (size_t)(p*32 + srow)*CH + (k0+64) + scol, &Bs[cur^1][p*2048 + w*512]);
      }
    }
    #pragma unroll
    for (int kk = 0; kk < 2; ++kk) {
      bf16x8 af[4], bfr[4];
      #pragma unroll
      for (int m = 0; m < 4; ++m)
        af[m] = *(const bf16x8*)&As[cur][(wm*64 + m*16 + qi)*64 + kk*32 + g*8];
      #pragma unroll
      for (int n = 0; n < 4; ++n)
        bfr[n] = *(const bf16x8*)&Bs[cur][(wn*64 + n*16 + qi)*64 + kk*32 + g*8];
      #pragma unroll
      for (int m = 0; m < 4; ++m)
        #pragma unroll
        for (int n = 0; n < 4; ++n)
          acc[m][n] = __builtin_amdgcn_mfma_f32_16x16x32_bf16(af[m], bfr[n], acc[m][n], 0, 0, 0);
    }
    __syncthreads();
    cur ^= 1;
  }

  #pragma unroll
  for (int m = 0; m < 4; ++m) {
    const int row0 = bm*128 + wm*64 + m*16 + g*4;
    #pragma unroll
    for (int n = 0; n < 4; ++n) {
      const int col = bn*128 + wn*64 + n*16 + qi;
      const float bv = bias[col];
      #pragma unroll
      for (int r = 0; r < 4; ++r)
        out[(size_t)(row0 + r)*CH + col] = acc[m][n][r] + bv;
    }
  }
}

// ---------- causal flash attention v5: KVBLK=128 ----------
// grid 32 x 8, 512 thr (8 waves x 16 q-rows), q-tile 128, pairs {p, 15-p}
// -> uniform 17 kt-iterations per block. Each iteration processes TWO 64-key
// sub-tiles (a/b) from one 128-key staged K/V tile: 32 MFMA + one combined
// 32-elem softmax per wave between barriers (2x amortization of the fixed
// per-iteration cost: barrier drain, stage latency, P round-trip).
// K tile [128][64] swizzled (col ^ (row&7)*8); V^T tile [64][128] swizzled
// (key ^ (d&15)*8). Per-lane-partial online softmax w/ defer-max (mrun is
// g-uniform by induction). Branchless tail masking: a: lk>lqa, b: lk>lqa-64.
__global__ __launch_bounds__(512) void csa_attn(
    const u16* __restrict__ qb, const u16* __restrict__ kb,
    const u16* __restrict__ vtb, u16* __restrict__ yout)
{
  const int bh = blockIdx.x, pair = blockIdx.y;
  const int bidx = bh >> 4, h = bh & 15;
  const int t = threadIdx.x, lane = t & 63, w = t >> 6;   // w 0..7
  const int g = lane >> 4, qi = lane & 15;
  __shared__ __align__(16) u16 Ks[2][128*64];   // 32 KB
  __shared__ __align__(16) u16 Vs[2][64*128];   // 32 KB, V^T [d][key]
  __shared__ __align__(16) u16 Ps[8][2][16*64]; // 32 KB, per-wave P [sub][q][key]

  const size_t kvbase = (size_t)bh * SEQ * HDIM;   // == bh*HDIM*SEQ for vtb
  const u16* kb_bh  = kb  + kvbase;
  const u16* vtb_bh = vtb + kvbase;

  // staging geometry (pass-independent swizzled source columns)
  const int krow_  = t >> 3;                                  // 0..63
  const int kcolsw = ((t & 7) * 8) ^ ((krow_ & 7) * 8);
  const int vd_    = t >> 4;                                  // 0..31
  const int vcolsw = ((t & 15) * 8) ^ ((vd_ & 15) * 8);

  // LDS read offsets
  int offKb[2][4], offVb[2][4], offPw[4], offPr[2];
  #pragma unroll
  for (int c = 0; c < 2; ++c) {
    offPr[c] = qi*64 + ((c*32 + g*8) ^ ((qi & 7) * 8));
    #pragma unroll
    for (int s4 = 0; s4 < 4; ++s4)
      offKb[c][s4] = (s4*16 + qi)*64 + ((c*32 + g*8) ^ ((qi & 7) * 8));
    #pragma unroll
    for (int nf = 0; nf < 4; ++nf)
      offVb[c][nf] = (nf*16 + qi)*128 + ((c*32 + g*8) ^ (qi * 8));
  }
  #pragma unroll
  for (int s4 = 0; s4 < 4; ++s4)
    offPw[s4] = qi*64 + ((s4*16 + g*4) ^ ((qi & 7) * 8));

  const float QSCALE = 0.18033688011112042f;   // 0.125 * log2(e)
  const int lqa = w*16 + qi;                   // wave-local q row (0..127)

  for (int half = 0; half < 2; ++half) {
    const int qt = half ? (15 - pair) : pair;
    const int qrow = qt*128 + w*16;
    const int ntile = qt + 1;            // 128-key tiles

    // Q fragment, pre-scaled by 0.125*log2e (exp2-domain softmax)
    bf16x8 qf[2];
    #pragma unroll
    for (int c = 0; c < 2; ++c) {
      qf[c] = *(const bf16x8*)&qb[(kvbase + (size_t)(qrow + qi)*HDIM) + c*32 + g*8];
      #pragma unroll
      for (int e = 0; e < 8; ++e)
        qf[c][e] = (short)f2b(b2f((u16)qf[c][e]) * QSCALE);
    }

    f32x4 yacc[4] = {};
    float mrun = -1e30f, srun = 0.f;     // per-lane partials (g-uniform mrun)

    __syncthreads();                     // all prior-tile reads done
    // prologue: stage tile 0 into buf 0
    {
      const u16* kp = kb_bh;
      gload_lds16(kp + (size_t)krow_*64 + kcolsw,        &Ks[0][       w*512]);
      gload_lds16(kp + (size_t)(64 + krow_)*64 + kcolsw, &Ks[0][4096 + w*512]);
      const u16* vp = vtb_bh;
      gload_lds16(vp + (size_t)vd_*SEQ + vcolsw,         &Vs[0][       w*512]);
      gload_lds16(vp + (size_t)(32 + vd_)*SEQ + vcolsw,  &Vs[0][4096 + w*512]);
    }
    __syncthreads();

    int buf = 0;
    for (int kt = 0; kt < ntile; ++kt) {
      // stage tile kt+1 into buf^1 (flies under compute; drained at barrier)
      if (kt + 1 < ntile) {
        const u16* kp = kb_bh + (size_t)((kt + 1) * 128) * 64;
        gload_lds16(kp + (size_t)krow_*64 + kcolsw,        &Ks[buf^1][       w*512]);
        gload_lds16(kp + (size_t)(64 + krow_)*64 + kcolsw, &Ks[buf^1][4096 + w*512]);
        const u16* vp = vtb_bh + (kt + 1) * 128;
        gload_lds16(vp + (size_t)vd_*SEQ + vcolsw,         &Vs[buf^1][       w*512]);
        gload_lds16(vp + (size_t)(32 + vd_)*SEQ + vcolsw,  &Vs[buf^1][4096 + w*512]);
      }

      // QK^T: two independent 64-key sub-tiles
      f32x4 sa[4] = {}, sb[4] = {};
      #pragma unroll
      for (int c = 0; c < 2; ++c)
        #pragma unroll
        for (int s4 = 0; s4 < 4; ++s4) {
          bf16x8 ka = *(const bf16x8*)&Ks[buf][offKb[c][s4]];
          sa[s4] = __builtin_amdgcn_mfma_f32_16x16x32_bf16(ka, qf[c], sa[s4], 0, 0, 0);
        }
      #pragma unroll
      for (int c = 0; c < 2; ++c)
        #pragma unroll
        for (int s4 = 0; s4 < 4; ++s4) {
          bf16x8 kbv = *(const bf16x8*)&Ks[buf][4096 + offKb[c][s4]];
          sb[s4] = __builtin_amdgcn_mfma_f32_16x16x32_bf16(kbv, qf[c], sb[s4], 0, 0, 0);
        }

      // diagonal-tile causal mask (branchless across waves)
      if (kt == ntile - 1) {
        #pragma unroll
        for (int s4 = 0; s4 < 4; ++s4)
          #pragma unroll
          for (int r = 0; r < 4; ++r) {
            const int lk = s4*16 + g*4 + r;
            if (lk > lqa)      sa[s4][r] = -3.0e38f;
            if (lk > lqa - 64) sb[s4][r] = -3.0e38f;
          }
      }

      // combined 32-elem online softmax (exp2 domain), defer-max
      float tmax = sa[0][0];
      #pragma unroll
      for (int s4 = 0; s4 < 4; ++s4)
        #pragma unroll
        for (int r = 0; r < 4; ++r) {
          tmax = fmaxf(tmax, sa[s4][r]);
          tmax = fmaxf(tmax, sb[s4][r]);
        }
      if (!__all(tmax - mrun <= 11.5f)) {   // rare: true rescale
        float tmf = fmaxf(tmax, __shfl_xor(tmax, 16));
        tmf = fmaxf(tmf, __shfl_xor(tmf, 32));
        float mnew = fmaxf(mrun, tmf);
        float fac = exp2_fast(mrun - mnew);
        #pragma unroll
        for (int r = 0; r < 4; ++r) {
          float fr = __shfl(fac, g*4 + r);
          #pragma unroll
          for (int nf = 0; nf < 4; ++nf) yacc[nf][r] *= fr;
        }
        srun *= fac;
        mrun = mnew;
      }
      float tsum = 0.f;
      #pragma unroll
      for (int s4 = 0; s4 < 4; ++s4)
        #pragma unroll
        for (int r = 0; r < 4; ++r) {
          float pa = exp2_fast(sa[s4][r] - mrun);
          float pb = exp2_fast(sb[s4][r] - mrun);
          sa[s4][r] = pa; sb[s4][r] = pb;
          tsum += pa + pb;
        }
      srun += tsum;                        // per-lane partial

      // P -> per-wave LDS (two sub-buffers; same-wave, no barrier)
      #pragma unroll
      for (int s4 = 0; s4 < 4; ++s4) {
        uint2 pwa, pwb;
        pwa.x = cvt_pk_bf16(sa[s4][0], sa[s4][1]);
        pwa.y = cvt_pk_bf16(sa[s4][2], sa[s4][3]);
        pwb.x = cvt_pk_bf16(sb[s4][0], sb[s4][1]);
        pwb.y = cvt_pk_bf16(sb[s4][2], sb[s4][3]);
        *(uint2*)&Ps[w][0][offPw[s4]] = pwa;
        *(uint2*)&Ps[w][1][offPw[s4]] = pwb;
      }

      // O += P_a * V_a + P_b * V_b
      #pragma unroll
      for (int c = 0; c < 2; ++c) {
        bf16x8 pa0 = *(const bf16x8*)&Ps[w][0][offPr[c]];
        bf16x8 pb0 = *(const bf16x8*)&Ps[w][1][offPr[c]];
        #pragma unroll
        for (int nf = 0; nf < 4; ++nf) {
          bf16x8 va = *(const bf16x8*)&Vs[buf][offVb[c][nf]];
          yacc[nf] = __builtin_amdgcn_mfma_f32_16x16x32_bf16(pa0, va, yacc[nf], 0, 0, 0);
          bf16x8 vb = *(const bf16x8*)&Vs[buf][offVb[c][nf] ^ 64];
          yacc[nf] = __builtin_amdgcn_mfma_f32_16x16x32_bf16(pb0, vb, yacc[nf], 0, 0, 0);
        }
      }

      __syncthreads();   // drains prefetch (vmcnt) + guards buf reuse
      buf ^= 1;
    }

    // epilogue: reduce per-lane partial sums across the 4 g-groups
    float srf = srun + __shfl_xor(srun, 16);
    srf += __shfl_xor(srf, 32);
    #pragma unroll
    for (int r = 0; r < 4; ++r) {
      float sv = __shfl(srf, g*4 + r);
      float inv = 1.f / sv;
      int qg = qrow + g*4 + r;
      #pragma unroll
      for (int nf = 0; nf < 4; ++nf) {
        int d = nf*16 + qi;
        yout[((size_t)bidx*SEQ + qg)*CH + h*HDIM + d] = f2b(yacc[nf][r] * inv);
      }
    }
  }
}

extern "C" void kernel_launch(void* const* d_in, const int* in_sizes, int n_in,
                              void* d_out, int out_size, void* d_ws, size_t ws_size,
                              hipStream_t stream) {
  (void)in_sizes; (void)n_in; (void)out_size; (void)ws_size;
  const float* x      = (const float*)d_in[0];
  const float* w_attn = (const float*)d_in[1];
  const float* b_attn = (const float*)d_in[2];
  const float* w_proj = (const float*)d_in[3];
  const float* b_proj = (const float*)d_in[4];

  char* ws = (char*)d_ws;
  const size_t MB = 1024*1024;
  u16* xb  = (u16*)(ws);             // 8 MB, reused as attention out y
  u16* wat = (u16*)(ws +  8*MB);     // 6 MB  w_attn^T [3072][1024]
  u16* wpt = (u16*)(ws + 14*MB);     // 2 MB  w_proj^T [1024][1024]
  u16* qb  = (u16*)(ws + 16*MB);     // 8 MB  [bh][t][64]
  u16* kb  = (u16*)(ws + 24*MB);     // 8 MB  [bh][t][64]
  u16* vtb = (u16*)(ws + 32*MB);     // 8 MB  [bh][64][t]

  csa_convert_x<<<2048, 256, 0, stream>>>(x, xb, ROWS*CH/8);
  csa_transpose2<<<dim3(128, 32), dim3(32, 8), 0, stream>>>(w_attn, w_proj, wat, wpt);
  csa_gemm_qkv<<<dim3(16, 16), 512, 0, stream>>>(xb, wat, b_attn, qb, kb, vtb);
  csa_attn<<<dim3(32, 8), 512, 0, stream>>>(qb, kb, vtb, xb);
  csa_gemm_proj<<<dim3(8, 32), 256, 0, stream>>>(xb, wpt, b_proj, (float*)d_out);
}

// Round 9
// 99.378 us; speedup vs baseline: 1.2044x; 1.1159x over previous
//
#include <hip/hip_runtime.h>

typedef unsigned short u16;
typedef short bf16x8 __attribute__((ext_vector_type(8)));
typedef float f32x4 __attribute__((ext_vector_type(4)));

#define BATCH 2
#define SEQ   2048
#define CH    1024
#define NHEAD 16
#define HDIM  64
#define ROWS  (BATCH*SEQ)   // 4096

#define WAITV(N) asm volatile("s_waitcnt vmcnt(" #N ")" ::: "memory")

__device__ __forceinline__ u16 f2b(float f) {
  unsigned u = __builtin_bit_cast(unsigned, f);
  u += 0x7FFFu + ((u >> 16) & 1u);
  return (u16)(u >> 16);
}
__device__ __forceinline__ float b2f(u16 h) {
  unsigned u = ((unsigned)h) << 16;
  return __builtin_bit_cast(float, u);
}
__device__ __forceinline__ float exp2_fast(float x) {
  float r; asm("v_exp_f32 %0, %1" : "=v"(r) : "v"(x)); return r;
}
__device__ __forceinline__ unsigned cvt_pk_bf16(float a, float b) {
  unsigned r; asm("v_cvt_pk_bf16_f32 %0, %1, %2" : "=v"(r) : "v"(a), "v"(b)); return r;
}

__device__ __forceinline__ void gload_lds16(const void* g, void* l) {
  __builtin_amdgcn_global_load_lds(
      (const __attribute__((address_space(1))) unsigned int*)g,
      (__attribute__((address_space(3))) unsigned int*)l, 16, 0, 0);
}

// ---------- fused prep: x f32->bf16, both weight transposes (one launch) ----
__global__ void csa_prep(const float* __restrict__ x,
                         const float* __restrict__ wa, const float* __restrict__ wp,
                         u16* __restrict__ xb, u16* __restrict__ wat,
                         u16* __restrict__ wpt) {
  __shared__ float tile[32][33];
  const int b = blockIdx.x, t = threadIdx.x;
  if (b < 2048) {               // convert x: 524288 uint4-pairs
    int i = b * 256 + t;
    const float4* f4 = (const float4*)x;
    float4 v0 = f4[2*i], v1 = f4[2*i+1];
    ushort4 o0, o1;
    o0.x = f2b(v0.x); o0.y = f2b(v0.y); o0.z = f2b(v0.z); o0.w = f2b(v0.w);
    o1.x = f2b(v1.x); o1.y = f2b(v1.y); o1.z = f2b(v1.z); o1.w = f2b(v1.w);
    ((ushort4*)xb)[2*i]   = o0;
    ((ushort4*)xb)[2*i+1] = o1;
    return;
  }
  int bb = b - 2048;            // transpose: 4096 blocks (128 x 32)
  int bx = bb & 127, by = bb >> 7;
  const float* in; u16* out; int C;
  if (bx < 96) { in = wa; out = wat; C = 3*CH; }
  else         { in = wp; out = wpt; C = CH; bx -= 96; }
  const int R = CH;
  const int bxc = bx * 32, byc = by * 32;
  const int tx = t & 31, ty = t >> 5;
  #pragma unroll
  for (int j = 0; j < 4; ++j) {
    int r = byc + ty + j*8, c = bxc + tx;
    tile[ty + j*8][tx] = in[(size_t)r*C + c];
  }
  __syncthreads();
  #pragma unroll
  for (int j = 0; j < 4; ++j) {
    int oc = bxc + ty + j*8;
    int orr = byc + tx;
    out[(size_t)oc*R + orr] = f2b(tile[tx][ty + j*8]);
  }
}

// ---------- QKV GEMM: [4096][3072] = xb * wat^T + b -------------------------
// BM=256, BN=192, BK=64; 512 thr = 8 waves (2M x 4N); grid 16x16 = 1/CU.
// Counted-vmcnt pipeline (T4): A triple-buffered (2-iter latency cover),
// B double-buffered; raw s_barrier x2/iter, NO vmcnt(0) drain in main loop.
// T2 XOR swizzle on LDS tiles (read 16-way conflict -> 2-way free):
// stage pre-swizzles the global source column; reads XOR with (qi&7)*8.
__global__ __launch_bounds__(512) void csa_gemm_qkv(
    const u16* __restrict__ A, const u16* __restrict__ Bt,
    const float* __restrict__ bias,
    u16* __restrict__ qbo, u16* __restrict__ kb, u16* __restrict__ vtb)
{
  __shared__ __align__(16) u16 As[3][256*64];   // 96 KB
  __shared__ __align__(16) u16 Bs[2][192*64];   // 48 KB
  const int t = threadIdx.x, lane = t & 63, w = t >> 6;
  const int wm = w >> 2, wn = w & 3, g = lane >> 4, qi = lane & 15;
  const int xq = (qi & 7) * 8;

  // bijective 2D-chunk XCD swizzle over the 16x16 grid
  const int wgid = blockIdx.y * 16 + blockIdx.x;
  const int c8 = wgid & 7, inner = wgid >> 3;
  const int bm = (c8 >> 1) * 4 + (inner >> 3);
  const int bn = (c8 & 1) * 8 + (inner & 7);

  f32x4 acc[8][3] = {};

  const u16* Ab = A  + (size_t)(bm*256)*CH;
  const u16* Bb = Bt + (size_t)(bn*192)*CH;
  const int srow = t >> 3;                               // 0..63
  const int scolsw = ((t & 7) * 8) ^ ((srow & 7) * 8);   // pre-swizzled src col

#define QKV_STAGE_A(kt_, buf_) do { const size_t k_ = (size_t)(kt_)*64;            \
    gload_lds16(Ab + (size_t)(  0 + srow)*CH + k_ + scolsw, &As[buf_][      w*512]); \
    gload_lds16(Ab + (size_t)( 64 + srow)*CH + k_ + scolsw, &As[buf_][ 4096+w*512]); \
    gload_lds16(Ab + (size_t)(128 + srow)*CH + k_ + scolsw, &As[buf_][ 8192+w*512]); \
    gload_lds16(Ab + (size_t)(192 + srow)*CH + k_ + scolsw, &As[buf_][12288+w*512]); \
  } while (0)
#define QKV_STAGE_B(kt_, buf_) do { const size_t k_ = (size_t)(kt_)*64;            \
    gload_lds16(Bb + (size_t)(  0 + srow)*CH + k_ + scolsw, &Bs[buf_][      w*512]); \
    gload_lds16(Bb + (size_t)( 64 + srow)*CH + k_ + scolsw, &Bs[buf_][ 4096+w*512]); \
    gload_lds16(Bb + (size_t)(128 + srow)*CH + k_ + scolsw, &Bs[buf_][ 8192+w*512]); \
  } while (0)

  // prologue (FIFO order matters for vmcnt counting): A(0), B(0), A(1)
  QKV_STAGE_A(0, 0); QKV_STAGE_B(0, 0); QKV_STAGE_A(1, 1);

  int a3 = 0;                                  // kt % 3
  for (int kt = 0; kt < 16; ++kt) {
    if (kt < 15) QKV_STAGE_B(kt + 1, (kt + 1) & 1);
    if (kt < 14) { int ab = a3 + 2; if (ab >= 3) ab -= 3; QKV_STAGE_A(kt + 2, ab); }
    // drain exactly {A(kt), B(kt)}: keep A(kt+1)[4] + B(kt+1)[3] + A(kt+2)[4]
    if (kt < 14)       WAITV(11);
    else if (kt == 14) WAITV(7);
    else               WAITV(0);
    __builtin_amdgcn_s_barrier();              // all waves' tile-kt loads landed
    __builtin_amdgcn_sched_barrier(0);         // pin ds_reads after the barrier
    const u16* Ac = &As[a3][0];
    const u16* Bc = &Bs[kt & 1][0];
    #pragma unroll
    for (int kk = 0; kk < 2; ++kk) {
      bf16x8 af[8], bfr[3];
      #pragma unroll
      for (int m = 0; m < 8; ++m)
        af[m] = *(const bf16x8*)&Ac[(wm*128 + m*16 + qi)*64 + ((kk*32 + g*8) ^ xq)];
      #pragma unroll
      for (int n = 0; n < 3; ++n)
        bfr[n] = *(const bf16x8*)&Bc[(wn*48 + n*16 + qi)*64 + ((kk*32 + g*8) ^ xq)];
      #pragma unroll
      for (int m = 0; m < 8; ++m)
        #pragma unroll
        for (int n = 0; n < 3; ++n)
          acc[m][n] = __builtin_amdgcn_mfma_f32_16x16x32_bf16(af[m], bfr[n], acc[m][n], 0, 0, 0);
    }
    __builtin_amdgcn_s_barrier();              // reads done -> buffers reusable
    a3 = (a3 == 2) ? 0 : a3 + 1;
  }
#undef QKV_STAGE_A
#undef QKV_STAGE_B

  // epilogue: scatter to q/k [bh][t][64] and v^T [bh][64][t]
  #pragma unroll
  for (int m = 0; m < 8; ++m) {
    const int row0 = bm*256 + wm*128 + m*16 + g*4;
    const int bb = row0 >> 11;
    const int t0 = row0 & 2047;
    #pragma unroll
    for (int n = 0; n < 3; ++n) {
      const int col = bn*192 + wn*48 + n*16 + qi;
      const float bv = bias[col];
      const int which = col >> 10;      // 0=q 1=k 2=v
      const int cc = col & 1023;
      const int h = cc >> 6, d = cc & 63;
      const int bh = bb*16 + h;
      if (which == 2) {
        ushort4 pw;
        pw.x = f2b(acc[m][n][0] + bv);
        pw.y = f2b(acc[m][n][1] + bv);
        pw.z = f2b(acc[m][n][2] + bv);
        pw.w = f2b(acc[m][n][3] + bv);
        *(ushort4*)&vtb[((size_t)bh*HDIM + d)*SEQ + t0] = pw;
      } else {
        u16* dst = (which == 0) ? qbo : kb;
        #pragma unroll
        for (int r = 0; r < 4; ++r)
          dst[((size_t)bh*SEQ + t0 + r)*HDIM + d] = f2b(acc[m][n][r] + bv);
      }
    }
  }
}

// ---------- proj GEMM: out[4096][1024] f32 = y * wpt^T + b ------------------
// 128x128 tile, 256 thr (4 waves 2x2); same T4 counted-vmcnt + T2 swizzle.
__global__ __launch_bounds__(256) void csa_gemm_proj(
    const u16* __restrict__ A, const u16* __restrict__ Bt,
    const float* __restrict__ bias, float* __restrict__ out)
{
  __shared__ __align__(16) u16 As[3][128*64];   // 48 KB
  __shared__ __align__(16) u16 Bs[2][128*64];   // 32 KB
  const int t = threadIdx.x, lane = t & 63, w = t >> 6;
  const int wm = w >> 1, wn = w & 1, g = lane >> 4, qi = lane & 15;
  const int xq = (qi & 7) * 8;
  const int bm = blockIdx.y, bn = blockIdx.x;

  f32x4 acc[4][4] = {};

  const u16* Ab = A  + (size_t)(bm*128)*CH;
  const u16* Bb = Bt + (size_t)(bn*128)*CH;
  const int srow = t >> 3;                               // 0..31
  const int scolsw = ((t & 7) * 8) ^ ((srow & 7) * 8);

#define PRJ_STAGE(P_, base_, kt_, buf_) do { const size_t k_ = (size_t)(kt_)*64;      \
    gload_lds16(P_ + (size_t)( 0 + srow)*CH + k_ + scolsw, &base_[buf_][     w*512]); \
    gload_lds16(P_ + (size_t)(32 + srow)*CH + k_ + scolsw, &base_[buf_][2048+w*512]); \
    gload_lds16(P_ + (size_t)(64 + srow)*CH + k_ + scolsw, &base_[buf_][4096+w*512]); \
    gload_lds16(P_ + (size_t)(96 + srow)*CH + k_ + scolsw, &base_[buf_][6144+w*512]); \
  } while (0)

  PRJ_STAGE(Ab, As, 0, 0); PRJ_STAGE(Bb, Bs, 0, 0); PRJ_STAGE(Ab, As, 1, 1);

  int a3 = 0;
  for (int kt = 0; kt < 16; ++kt) {
    if (kt < 15) PRJ_STAGE(Bb, Bs, kt + 1, (kt + 1) & 1);
    if (kt < 14) { int ab = a3 + 2; if (ab >= 3) ab -= 3; PRJ_STAGE(Ab, As, kt + 2, ab); }
    if (kt < 14)       WAITV(12);   // keep A(kt+1)[4]+B(kt+1)[4]+A(kt+2)[4]
    else if (kt == 14) WAITV(8);
    else               WAITV(0);
    __builtin_amdgcn_s_barrier();
    __builtin_amdgcn_sched_barrier(0);
    const u16* Ac = &As[a3][0];
    const u16* Bc = &Bs[kt & 1][0];
    #pragma unroll
    for (int kk = 0; kk < 2; ++kk) {
      bf16x8 af[4], bfr[4];
      #pragma unroll
      for (int m = 0; m < 4; ++m)
        af[m] = *(const bf16x8*)&Ac[(wm*64 + m*16 + qi)*64 + ((kk*32 + g*8) ^ xq)];
      #pragma unroll
      for (int n = 0; n < 4; ++n)
        bfr[n] = *(const bf16x8*)&Bc[(wn*64 + n*16 + qi)*64 + ((kk*32 + g*8) ^ xq)];
      #pragma unroll
      for (int m = 0; m < 4; ++m)
        #pragma unroll
        for (int n = 0; n < 4; ++n)
          acc[m][n] = __builtin_amdgcn_mfma_f32_16x16x32_bf16(af[m], bfr[n], acc[m][n], 0, 0, 0);
    }
    __builtin_amdgcn_s_barrier();
    a3 = (a3 == 2) ? 0 : a3 + 1;
  }
#undef PRJ_STAGE

  #pragma unroll
  for (int m = 0; m < 4; ++m) {
    const int row0 = bm*128 + wm*64 + m*16 + g*4;
    #pragma unroll
    for (int n = 0; n < 4; ++n) {
      const int col = bn*128 + wn*64 + n*16 + qi;
      const float bv = bias[col];
      #pragma unroll
      for (int r = 0; r < 4; ++r)
        out[(size_t)(row0 + r)*CH + col] = acc[m][n][r] + bv;
    }
  }
}

// ---------- causal flash attention v5: KVBLK=128 (unchanged from round 8) ---
__global__ __launch_bounds__(512) void csa_attn(
    const u16* __restrict__ qb, const u16* __restrict__ kb,
    const u16* __restrict__ vtb, u16* __restrict__ yout)
{
  const int bh = blockIdx.x, pair = blockIdx.y;
  const int bidx = bh >> 4, h = bh & 15;
  const int t = threadIdx.x, lane = t & 63, w = t >> 6;   // w 0..7
  const int g = lane >> 4, qi = lane & 15;
  __shared__ __align__(16) u16 Ks[2][128*64];   // 32 KB
  __shared__ __align__(16) u16 Vs[2][64*128];   // 32 KB, V^T [d][key]
  __shared__ __align__(16) u16 Ps[8][2][16*64]; // 32 KB, per-wave P [sub][q][key]

  const size_t kvbase = (size_t)bh * SEQ * HDIM;
  const u16* kb_bh  = kb  + kvbase;
  const u16* vtb_bh = vtb + kvbase;

  const int krow_  = t >> 3;                                  // 0..63
  const int kcolsw = ((t & 7) * 8) ^ ((krow_ & 7) * 8);
  const int vd_    = t >> 4;                                  // 0..31
  const int vcolsw = ((t & 15) * 8) ^ ((vd_ & 15) * 8);

  int offKb[2][4], offVb[2][4], offPw[4], offPr[2];
  #pragma unroll
  for (int c = 0; c < 2; ++c) {
    offPr[c] = qi*64 + ((c*32 + g*8) ^ ((qi & 7) * 8));
    #pragma unroll
    for (int s4 = 0; s4 < 4; ++s4)
      offKb[c][s4] = (s4*16 + qi)*64 + ((c*32 + g*8) ^ ((qi & 7) * 8));
    #pragma unroll
    for (int nf = 0; nf < 4; ++nf)
      offVb[c][nf] = (nf*16 + qi)*128 + ((c*32 + g*8) ^ (qi * 8));
  }
  #pragma unroll
  for (int s4 = 0; s4 < 4; ++s4)
    offPw[s4] = qi*64 + ((s4*16 + g*4) ^ ((qi & 7) * 8));

  const float QSCALE = 0.18033688011112042f;   // 0.125 * log2(e)
  const int lqa = w*16 + qi;

  for (int half = 0; half < 2; ++half) {
    const int qt = half ? (15 - pair) : pair;
    const int qrow = qt*128 + w*16;
    const int ntile = qt + 1;

    bf16x8 qf[2];
    #pragma unroll
    for (int c = 0; c < 2; ++c) {
      qf[c] = *(const bf16x8*)&qb[(kvbase + (size_t)(qrow + qi)*HDIM) + c*32 + g*8];
      #pragma unroll
      for (int e = 0; e < 8; ++e)
        qf[c][e] = (short)f2b(b2f((u16)qf[c][e]) * QSCALE);
    }

    f32x4 yacc[4] = {};
    float mrun = -1e30f, srun = 0.f;

    __syncthreads();
    {
      const u16* kp = kb_bh;
      gload_lds16(kp + (size_t)krow_*64 + kcolsw,        &Ks[0][       w*512]);
      gload_lds16(kp + (size_t)(64 + krow_)*64 + kcolsw, &Ks[0][4096 + w*512]);
      const u16* vp = vtb_bh;
      gload_lds16(vp + (size_t)vd_*SEQ + vcolsw,         &Vs[0][       w*512]);
      gload_lds16(vp + (size_t)(32 + vd_)*SEQ + vcolsw,  &Vs[0][4096 + w*512]);
    }
    __syncthreads();

    int buf = 0;
    for (int kt = 0; kt < ntile; ++kt) {
      if (kt + 1 < ntile) {
        const u16* kp = kb_bh + (size_t)((kt + 1) * 128) * 64;
        gload_lds16(kp + (size_t)krow_*64 + kcolsw,        &Ks[buf^1][       w*512]);
        gload_lds16(kp + (size_t)(64 + krow_)*64 + kcolsw, &Ks[buf^1][4096 + w*512]);
        const u16* vp = vtb_bh + (kt + 1) * 128;
        gload_lds16(vp + (size_t)vd_*SEQ + vcolsw,         &Vs[buf^1][       w*512]);
        gload_lds16(vp + (size_t)(32 + vd_)*SEQ + vcolsw,  &Vs[buf^1][4096 + w*512]);
      }

      f32x4 sa[4] = {}, sb[4] = {};
      #pragma unroll
      for (int c = 0; c < 2; ++c)
        #pragma unroll
        for (int s4 = 0; s4 < 4; ++s4) {
          bf16x8 ka = *(const bf16x8*)&Ks[buf][offKb[c][s4]];
          sa[s4] = __builtin_amdgcn_mfma_f32_16x16x32_bf16(ka, qf[c], sa[s4], 0, 0, 0);
        }
      #pragma unroll
      for (int c = 0; c < 2; ++c)
        #pragma unroll
        for (int s4 = 0; s4 < 4; ++s4) {
          bf16x8 kbv = *(const bf16x8*)&Ks[buf][4096 + offKb[c][s4]];
          sb[s4] = __builtin_amdgcn_mfma_f32_16x16x32_bf16(kbv, qf[c], sb[s4], 0, 0, 0);
        }

      if (kt == ntile - 1) {
        #pragma unroll
        for (int s4 = 0; s4 < 4; ++s4)
          #pragma unroll
          for (int r = 0; r < 4; ++r) {
            const int lk = s4*16 + g*4 + r;
            if (lk > lqa)      sa[s4][r] = -3.0e38f;
            if (lk > lqa - 64) sb[s4][r] = -3.0e38f;
          }
      }

      float tmax = sa[0][0];
      #pragma unroll
      for (int s4 = 0; s4 < 4; ++s4)
        #pragma unroll
        for (int r = 0; r < 4; ++r) {
          tmax = fmaxf(tmax, sa[s4][r]);
          tmax = fmaxf(tmax, sb[s4][r]);
        }
      if (!__all(tmax - mrun <= 11.5f)) {
        float tmf = fmaxf(tmax, __shfl_xor(tmax, 16));
        tmf = fmaxf(tmf, __shfl_xor(tmf, 32));
        float mnew = fmaxf(mrun, tmf);
        float fac = exp2_fast(mrun - mnew);
        #pragma unroll
        for (int r = 0; r < 4; ++r) {
          float fr = __shfl(fac, g*4 + r);
          #pragma unroll
          for (int nf = 0; nf < 4; ++nf) yacc[nf][r] *= fr;
        }
        srun *= fac;
        mrun = mnew;
      }
      float tsum = 0.f;
      #pragma unroll
      for (int s4 = 0; s4 < 4; ++s4)
        #pragma unroll
        for (int r = 0; r < 4; ++r) {
          float pa = exp2_fast(sa[s4][r] - mrun);
          float pb = exp2_fast(sb[s4][r] - mrun);
          sa[s4][r] = pa; sb[s4][r] = pb;
          tsum += pa + pb;
        }
      srun += tsum;

      #pragma unroll
      for (int s4 = 0; s4 < 4; ++s4) {
        uint2 pwa, pwb;
        pwa.x = cvt_pk_bf16(sa[s4][0], sa[s4][1]);
        pwa.y = cvt_pk_bf16(sa[s4][2], sa[s4][3]);
        pwb.x = cvt_pk_bf16(sb[s4][0], sb[s4][1]);
        pwb.y = cvt_pk_bf16(sb[s4][2], sb[s4][3]);
        *(uint2*)&Ps[w][0][offPw[s4]] = pwa;
        *(uint2*)&Ps[w][1][offPw[s4]] = pwb;
      }

      #pragma unroll
      for (int c = 0; c < 2; ++c) {
        bf16x8 pa0 = *(const bf16x8*)&Ps[w][0][offPr[c]];
        bf16x8 pb0 = *(const bf16x8*)&Ps[w][1][offPr[c]];
        #pragma unroll
        for (int nf = 0; nf < 4; ++nf) {
          bf16x8 va = *(const bf16x8*)&Vs[buf][offVb[c][nf]];
          yacc[nf] = __builtin_amdgcn_mfma_f32_16x16x32_bf16(pa0, va, yacc[nf], 0, 0, 0);
          bf16x8 vb = *(const bf16x8*)&Vs[buf][offVb[c][nf] ^ 64];
          yacc[nf] = __builtin_amdgcn_mfma_f32_16x16x32_bf16(pb0, vb, yacc[nf], 0, 0, 0);
        }
      }

      __syncthreads();
      buf ^= 1;
    }

    float srf = srun + __shfl_xor(srun, 16);
    srf += __shfl_xor(srf, 32);
    #pragma unroll
    for (int r = 0; r < 4; ++r) {
      float sv = __shfl(srf, g*4 + r);
      float inv = 1.f / sv;
      int qg = qrow + g*4 + r;
      #pragma unroll
      for (int nf = 0; nf < 4; ++nf) {
        int d = nf*16 + qi;
        yout[((size_t)bidx*SEQ + qg)*CH + h*HDIM + d] = f2b(yacc[nf][r] * inv);
      }
    }
  }
}

extern "C" void kernel_launch(void* const* d_in, const int* in_sizes, int n_in,
                              void* d_out, int out_size, void* d_ws, size_t ws_size,
                              hipStream_t stream) {
  (void)in_sizes; (void)n_in; (void)out_size; (void)ws_size;
  const float* x      = (const float*)d_in[0];
  const float* w_attn = (const float*)d_in[1];
  const float* b_attn = (const float*)d_in[2];
  const float* w_proj = (const float*)d_in[3];
  const float* b_proj = (const float*)d_in[4];

  char* ws = (char*)d_ws;
  const size_t MB = 1024*1024;
  u16* xb  = (u16*)(ws);             // 8 MB, reused as attention out y
  u16* wat = (u16*)(ws +  8*MB);     // 6 MB  w_attn^T [3072][1024]
  u16* wpt = (u16*)(ws + 14*MB);     // 2 MB  w_proj^T [1024][1024]
  u16* qb  = (u16*)(ws + 16*MB);     // 8 MB  [bh][t][64]
  u16* kb  = (u16*)(ws + 24*MB);     // 8 MB  [bh][t][64]
  u16* vtb = (u16*)(ws + 32*MB);     // 8 MB  [bh][64][t]

  csa_prep<<<6144, 256, 0, stream>>>(x, w_attn, w_proj, xb, wat, wpt);
  csa_gemm_qkv<<<dim3(16, 16), 512, 0, stream>>>(xb, wat, b_attn, qb, kb, vtb);
  csa_attn<<<dim3(32, 8), 512, 0, stream>>>(qb, kb, vtb, xb);
  csa_gemm_proj<<<dim3(8, 32), 256, 0, stream>>>(xb, wpt, b_proj, (float*)d_out);
}